// Round 10
// baseline (84.337 us; speedup 1.0000x reference)
//
#include <hip/hip_runtime.h>
#include <math.h>

#define EPSF 1e-6f
#define ACH 512      // anchors per k_fpart block
#define NBIN 1024    // conf histogram bins
#define CAP 8192     // cutoff-bucket capacity (expected ~64 for uniform conf)
#define CAPB 64      // per-target per-block candidate buffer
#define BIASU 0x4000000000000000ull

struct Part { unsigned long long q0, q1, q2, cand; };

__device__ __forceinline__ double u2d(unsigned long long x){return __longlong_as_double((long long)x);}
__device__ __forceinline__ unsigned long long d2u(double x){return (unsigned long long)__double_as_longlong(x);}

// branchless sorted-insert into descending triple; keys are positive doubles
// (bit62 bias, f32-iou bits occupy bits 32..61) so f64 order == u64 order.
__device__ __forceinline__ void ins3d(double p, double &q0, double &q1, double &q2) {
  double n0 = fmax(q0,p), x = fmin(q0,p);
  double n1 = fmax(q1,x), y = fmin(q1,x);
  double n2 = fmax(q2,y);
  q0=n0; q1=n1; q2=n2;
}

__device__ __forceinline__ float focal_neg(float c) {
  float pt = 1.f - c;
  float ptc = fminf(fmaxf(pt, EPSF), 1.f - EPSF);
  float om = 1.f - pt;
  return -0.75f * om * om * logf(ptc);
}

// Fused per-(512-anchor-chunk, image) kernel. Each thread holds 2 anchors in
// registers; targets are block-uniform loads. One IoU core per pair feeds BOTH
// per-anchor argmax (cross-mult compare; precise div at end, np-bitwise) and
// the candidate test (iou>0.3; rcp-approx key, ordering only). Candidates
// (~2% of lanes) push packed keys to per-target LDS buffers; 32-thread merge
// folds to top-3. Exact counts; exact fallback rescans overflowed targets.
// Absorbs k_zero. __launch_bounds__(256,4): 128-VGPR budget — the bare (256)
// version register-starved to 32 VGPRs and rematerialized ~4x the issues.
__global__ __launch_bounds__(256, 4) void k_fpart(
    const float4* __restrict__ anchors, const float4* __restrict__ tboxes,
    Part* __restrict__ parts, float* __restrict__ maxIou, unsigned char* __restrict__ bestT,
    unsigned char* __restrict__ forced, unsigned* __restrict__ gh,
    unsigned* __restrict__ accW, int naccW, float* __restrict__ out,
    int A, int T, int nch) {
  __shared__ unsigned long long buf[32][CAPB+1];
  __shared__ unsigned cnt[32];
  int chunk = blockIdx.x, b = blockIdx.y;
  int tid = threadIdx.x;
  int base = chunk * ACH;
  // ---- absorbed zero duties ----
  if (tid < 32) cnt[tid] = 0;
  if (tid < 128) ((unsigned*)(forced + (size_t)b*A + base))[tid] = 0u;
  if (chunk < 4) gh[b*NBIN + chunk*256 + tid] = 0u;
  if (chunk == 4 && b == 0) {
    if (tid < naccW) accW[tid] = 0u;
    if (tid == 0) out[0] = 0.f;
  }
  // ---- anchors to registers (coalesced) ----
  int i0 = base + tid, i1 = base + tid + 256;
  float4 a0 = anchors[i0], a1 = anchors[i1];
  float ar0 = (a0.z-a0.x)*(a0.w-a0.y);
  float ar1 = (a1.z-a1.x)*(a1.w-a1.y);
  float g0 = 0.3f*ar0, g1 = 0.3f*ar1;
  __syncthreads();           // cnt ready before pushes
  float bn0=-1.f, bd0=1.f; float bn1=-1.f, bd1=1.f;
  int bt0=0, bt1=0;
  #pragma unroll 4
  for (int tt = 0; tt < T; ++tt) {
    float4 tv = tboxes[b*T + tt];          // uniform
    float ta = (tv.z-tv.x)*(tv.w-tv.y);
    float cH = 0.3f*(ta + EPSF) - 1e-6f;   // conservative guard constant
    { // anchor 0
      float ix1=fmaxf(a0.x,tv.x), iy1=fmaxf(a0.y,tv.y);
      float ix2=fminf(a0.z,tv.z), iy2=fminf(a0.w,tv.w);
      float inter=fmaxf(ix2-ix1,0.f)*fmaxf(iy2-iy1,0.f);
      float u=(ar0+ta)-inter, d=u+EPSF;    // same op order as np
      bool gt = inter*bd0 > bn0*d;         // first-occurrence argmax kept on ties
      bn0=gt?inter:bn0; bd0=gt?d:bd0; bt0=gt?tt:bt0;
      if (__builtin_expect(1.3f*inter >= g0 + cH, 0)) {  // superset of iou>0.3
        float iou = inter * __builtin_amdgcn_rcpf(d);
        if (iou > 0.3f) {
          unsigned slot = atomicAdd(&cnt[tt], 1u);
          if (slot < CAPB)
            buf[tt][slot] = ((unsigned long long)__float_as_uint(iou)<<32)
                          | (unsigned long long)(0xFFFFFFFFu-(unsigned)i0) | BIASU;
        }
      }
    }
    { // anchor 1
      float ix1=fmaxf(a1.x,tv.x), iy1=fmaxf(a1.y,tv.y);
      float ix2=fminf(a1.z,tv.z), iy2=fminf(a1.w,tv.w);
      float inter=fmaxf(ix2-ix1,0.f)*fmaxf(iy2-iy1,0.f);
      float u=(ar1+ta)-inter, d=u+EPSF;
      bool gt = inter*bd1 > bn1*d;
      bn1=gt?inter:bn1; bd1=gt?d:bd1; bt1=gt?tt:bt1;
      if (__builtin_expect(1.3f*inter >= g1 + cH, 0)) {
        float iou = inter * __builtin_amdgcn_rcpf(d);
        if (iou > 0.3f) {
          unsigned slot = atomicAdd(&cnt[tt], 1u);
          if (slot < CAPB)
            buf[tt][slot] = ((unsigned long long)__float_as_uint(iou)<<32)
                          | (unsigned long long)(0xFFFFFFFFu-(unsigned)i1) | BIASU;
        }
      }
    }
  }
  size_t gb = (size_t)b * A;
  maxIou[gb+i0] = bn0/bd0; bestT[gb+i0] = (unsigned char)bt0;  // precise, np-bitwise
  maxIou[gb+i1] = bn1/bd1; bestT[gb+i1] = (unsigned char)bt1;
  __syncthreads();
  const double BIASD = u2d(BIASU);
  if (tid < 32 && tid < T) {               // per-target merge (entries ~10)
    unsigned n = cnt[tid];
    if (n <= CAPB) {
      double q0=BIASD, q1=BIASD, q2=BIASD;
      for (unsigned j = 0; j < n; ++j) ins3d(u2d(buf[tid][j]), q0,q1,q2);
      Part p; p.q0=d2u(q0); p.q1=d2u(q1); p.q2=d2u(q2); p.cand=n;
      parts[(b*T+tid)*nch+chunk] = p;
    }
  }
  if (tid < 64) {                          // exact overflow fallback (~never)
    unsigned long long ovf = __ballot(tid < T && cnt[tid] > CAPB);
    while (ovf) {
      int t = __ffsll(ovf) - 1;
      ovf &= ovf - 1;
      float4 tv = tboxes[b*T + t];
      float ta = (tv.z-tv.x)*(tv.w-tv.y);
      double q0=BIASD, q1=BIASD, q2=BIASD;
      for (int j = 0; j < ACH; j += 64) {
        int idx = base + j + tid;
        float4 an = anchors[idx];
        float aa = (an.z-an.x)*(an.w-an.y);
        float ix1=fmaxf(an.x,tv.x), iy1=fmaxf(an.y,tv.y);
        float ix2=fminf(an.z,tv.z), iy2=fminf(an.w,tv.w);
        float inter=fmaxf(ix2-ix1,0.f)*fmaxf(iy2-iy1,0.f);
        float iou = inter / ((aa+ta)-inter + EPSF);
        if (iou > 0.3f) {
          unsigned long long pk = ((unsigned long long)__float_as_uint(iou)<<32)
                                | (unsigned long long)(0xFFFFFFFFu-(unsigned)idx) | BIASU;
          ins3d(u2d(pk), q0,q1,q2);
        }
      }
      for (int s=1;s<64;s<<=1) {
        double r0=__shfl_xor(q0,s,64), r1=__shfl_xor(q1,s,64), r2=__shfl_xor(q2,s,64);
        ins3d(r0,q0,q1,q2); ins3d(r1,q0,q1,q2); ins3d(r2,q0,q1,q2);
      }
      if (tid == 0) {
        Part p; p.q0=d2u(q0); p.q1=d2u(q1); p.q2=d2u(q2); p.cand=cnt[t];
        parts[(b*T+t)*nch+chunk] = p;
      }
    }
  }
}

// one wave per (b,t): merge nch chunk-partials. cand>=1: forced = top-min(3,cand)
// (== reference, since forced set is within candidates). cand==0: exact argmax.
__global__ __launch_bounds__(64) void k_fmerge(
    const Part* __restrict__ parts, const float4* __restrict__ anchors,
    const float4* __restrict__ tboxes, unsigned char* __restrict__ forced,
    int A, int T, int nch) {
  int p = blockIdx.x;            // b*T + t
  int b = p / T, t = p - b*T;
  int lane = threadIdx.x;
  const double BIASD = u2d(BIASU);
  double q0=BIASD, q1=BIASD, q2=BIASD;
  unsigned long long cand = 0;
  for (int c = lane; c < nch; c += 64) {
    Part pp = parts[p*nch + c];
    ins3d(u2d(pp.q0),q0,q1,q2); ins3d(u2d(pp.q1),q0,q1,q2); ins3d(u2d(pp.q2),q0,q1,q2);
    cand += pp.cand;
  }
  for (int s = 1; s < 64; s <<= 1) {
    double r0=__shfl_xor(q0,s,64), r1=__shfl_xor(q1,s,64), r2=__shfl_xor(q2,s,64);
    unsigned long long rc=__shfl_xor(cand,s,64);
    ins3d(r0,q0,q1,q2); ins3d(r1,q0,q1,q2); ins3d(r2,q0,q1,q2);
    cand += rc;
  }
  if (cand == 0) {               // wave-uniform, ~never taken
    float4 tv = tboxes[b*T + t];
    float ta = (tv.z-tv.x)*(tv.w-tv.y);
    double m = BIASD;
    for (int a = lane; a < A; a += 64) {
      float4 an = anchors[a];
      float a1 = (an.z-an.x)*(an.w-an.y);
      float ix1=fmaxf(an.x,tv.x), iy1=fmaxf(an.y,tv.y);
      float ix2=fminf(an.z,tv.z), iy2=fminf(an.w,tv.w);
      float inter=fmaxf(ix2-ix1,0.f)*fmaxf(iy2-iy1,0.f);
      float u = (a1 + ta) - inter;
      float iou = inter / (u + EPSF);
      unsigned long long pk = ((unsigned long long)__float_as_uint(iou)<<32)
                            | (unsigned long long)(0xFFFFFFFFu-(unsigned)a) | BIASU;
      m = fmax(m, u2d(pk));
    }
    for (int s = 1; s < 64; s <<= 1) m = fmax(m, __shfl_xor(m, s, 64));
    if (lane == 0) {
      unsigned idx = 0xFFFFFFFFu - (unsigned)(d2u(m) & 0xFFFFFFFFull);
      forced[(size_t)b*A + idx] = 1;
    }
  } else if (lane == 0) {
    int kt = cand > 3 ? 3 : (int)cand;
    unsigned long long tp[3] = {d2u(q0), d2u(q1), d2u(q2)};
    for (int j = 0; j < kt; ++j) {
      unsigned idx = 0xFFFFFFFFu - (unsigned)(tp[j] & 0xFFFFFFFFull);
      forced[(size_t)b*A + idx] = 1;
    }
  }
}

// streaming: 16 anchors/thread. Reads maxIou/bestT/forced/conf (+bbox for positives),
// writes negConf, builds per-image conf histogram (LDS->global), accumulates
// focal/bbox sums + counts.
__global__ __launch_bounds__(256) void k_anchor2(
    const float4* __restrict__ bbox_pred, const float* __restrict__ conf_pred,
    const float4* __restrict__ tboxes,
    const unsigned char* __restrict__ forced, const float* __restrict__ maxIou,
    const unsigned char* __restrict__ bestT,
    float* __restrict__ negConf, unsigned* __restrict__ gh,
    float* __restrict__ accPos, float* __restrict__ accBbox,
    unsigned* __restrict__ cntPos, unsigned* __restrict__ cntNeg,
    int A, int T) {
  __shared__ float4 st[32];
  __shared__ unsigned h[NBIN];
  __shared__ float sP[256], sB[256];
  __shared__ int cP[256], cN[256];
  int b = blockIdx.y, tid = threadIdx.x;
  if (tid < T) st[tid] = tboxes[b*T+tid];
  for (int i = tid; i < NBIN; i += 256) h[i] = 0;
  __syncthreads();
  size_t ibase = (size_t)b*A + (size_t)blockIdx.x*4096;
  float fsum=0.f, bsum=0.f; int cpos=0, cneg=0;
  for (int it = 0; it < 4; ++it) {
    int off = it*1024 + tid*4;
    float4 mi4 = *(const float4*)(maxIou + ibase + off);
    float4 cf4 = *(const float4*)(conf_pred + ibase + off);
    uchar4 fc4 = *(const uchar4*)(forced + ibase + off);
    uchar4 bt4 = *(const uchar4*)(bestT + ibase + off);
    float mis[4]={mi4.x,mi4.y,mi4.z,mi4.w};
    float cfs[4]={cf4.x,cf4.y,cf4.z,cf4.w};
    unsigned char fcs[4]={fc4.x,fc4.y,fc4.z,fc4.w};
    unsigned char bts[4]={bt4.x,bt4.y,bt4.z,bt4.w};
    float nc[4];
    #pragma unroll
    for (int j=0;j<4;++j) {
      float maxI = mis[j], conf = cfs[j];
      bool isPos = (maxI >= 0.5f) || (fcs[j] != 0);
      bool isNeg = (maxI < 0.4f) && !isPos;
      nc[j] = isNeg ? conf : -1.f;
      if (isNeg) {
        int bin = min(NBIN-1, (int)(conf*1024.f));
        atomicAdd(&h[bin], 1u);
        cneg++;
      }
      if (isPos) {
        cpos++;
        float ptc = fminf(fmaxf(conf, EPSF), 1.f-EPSF);
        float om = 1.f - conf;
        fsum += -0.25f * om * om * logf(ptc);
        float4 pb = bbox_pred[ibase + off + j];
        float4 m = st[bts[j]];
        float ix1=fmaxf(pb.x,m.x), iy1=fmaxf(pb.y,m.y);
        float ix2=fminf(pb.z,m.z), iy2=fminf(pb.w,m.w);
        float inter=fmaxf(ix2-ix1,0.f)*fmaxf(iy2-iy1,0.f);
        float a1=(pb.z-pb.x)*(pb.w-pb.y);
        float a2=(m.z-m.x)*(m.w-m.y);
        float uni = a1 + a2 - inter;
        float iou = inter/(uni+EPSF);
        float ex1=fminf(pb.x,m.x), ey1=fminf(pb.y,m.y);
        float ex2=fmaxf(pb.z,m.z), ey2=fmaxf(pb.w,m.w);
        float enc=(ex2-ex1)*(ey2-ey1);
        float giou = iou - (enc-uni)/(enc+EPSF);
        float l1 = fabsf(pb.x-m.x)+fabsf(pb.y-m.y)+fabsf(pb.z-m.z)+fabsf(pb.w-m.w);
        bsum += (1.f - giou) + 0.125f*l1;
      }
    }
    *(float4*)(negConf + ibase + off) = make_float4(nc[0],nc[1],nc[2],nc[3]);
  }
  sP[tid]=fsum; sB[tid]=bsum; cP[tid]=cpos; cN[tid]=cneg;
  __syncthreads();
  for (int s=128;s>0;s>>=1) {
    if (tid<s){ sP[tid]+=sP[tid+s]; sB[tid]+=sB[tid+s]; cP[tid]+=cP[tid+s]; cN[tid]+=cN[tid+s]; }
    __syncthreads();
  }
  if (tid==0) {
    atomicAdd(&accPos[b], sP[0]);
    atomicAdd(&accBbox[b], sB[0]);
    atomicAdd(&cntPos[b], (unsigned)cP[0]);
    atomicAdd(&cntNeg[b], (unsigned)cN[0]);
  }
  for (int i = tid; i < NBIN; i += 256)
    if (h[i]) atomicAdd(&gh[b*NBIN + i], h[i]);
}

// 16 blocks/image: redundant parallel hist-scan -> selB/krem, then stream slice:
// focal-sum for bins > selB, collect cutoff-bucket members to global.
__global__ __launch_bounds__(256) void k_collect(
    const float* __restrict__ negConf, const unsigned* __restrict__ gh,
    const unsigned* __restrict__ cntPos, const unsigned* __restrict__ cntNeg,
    float* __restrict__ sumHi, unsigned* __restrict__ bucketCnt,
    unsigned* __restrict__ bucketBuf, unsigned* __restrict__ kremG,
    int A, int B) {
  __shared__ unsigned hh[NBIN];
  __shared__ unsigned partial[256];
  __shared__ int sSelB, sKrem;
  __shared__ float sred[256];
  int b = blockIdx.y, tid = threadIdx.x;
  int np = (int)cntPos[b], nn = (int)cntNeg[b];
  int ratio = (np>0) ? min(3, A/np) : 0;
  int k = min(ratio*np, nn);
  if (k <= 0) return;
  for (int i = tid; i < NBIN; i += 256) hh[i] = gh[b*NBIN+i];
  __syncthreads();
  unsigned own = hh[4*tid] + hh[4*tid+1] + hh[4*tid+2] + hh[4*tid+3];
  partial[tid] = own;
  __syncthreads();
  for (int off=1; off<256; off<<=1) {       // inclusive suffix scan (parallel)
    unsigned v = (tid+off<256) ? partial[tid+off] : 0u;
    __syncthreads();
    partial[tid] += v;
    __syncthreads();
  }
  {
    unsigned running = partial[tid] - own;  // sum of bins >= 4(tid+1)
    #pragma unroll
    for (int j=3;j>=0;--j) {
      unsigned incl = running + hh[4*tid+j];
      if (incl >= (unsigned)k && running < (unsigned)k) { sSelB = 4*tid+j; sKrem = k-(int)running; }
      running = incl;
    }
  }
  __syncthreads();
  int selB = sSelB, krem = sKrem;
  if (blockIdx.x==0 && tid==0) kremG[b] = (unsigned)krem;
  const float4* nc4 = (const float4*)(negConf + (size_t)b*A);
  int per4 = (A/4) / gridDim.x;
  int i0 = blockIdx.x * per4;
  float ls = 0.f;
  for (int i = tid; i < per4; i += 256) {
    float4 c4 = nc4[i0+i];
    float cs[4]={c4.x,c4.y,c4.z,c4.w};
    #pragma unroll
    for (int j=0;j<4;++j) {
      float c = cs[j];
      if (c >= 0.f) {
        int bin = min(NBIN-1, (int)(c*1024.f));
        if (bin > selB) ls += focal_neg(c);
        else if (bin == selB) {
          unsigned idx = atomicAdd(&bucketCnt[b], 1u);
          if (idx < CAP) bucketBuf[b*CAP+idx] = __float_as_uint(c);
        }
      }
    }
  }
  sred[tid]=ls; __syncthreads();
  for (int s=128;s>0;s>>=1){ if(tid<s) sred[tid]+=sred[tid+s]; __syncthreads(); }
  if (tid==0) atomicAdd(&sumHi[b], sred[0]);
}

// one block/image: fully parallel radix-select over the small bucket -> exact
// theta; finalize scalar.
__global__ __launch_bounds__(256) void k_resolve(
    const unsigned* __restrict__ bucketBuf, const unsigned* __restrict__ bucketCnt,
    const unsigned* __restrict__ kremG, const float* __restrict__ sumHi,
    const float* __restrict__ accPos, const float* __restrict__ accBbox,
    const unsigned* __restrict__ cntPos, const unsigned* __restrict__ cntNeg,
    float* __restrict__ out, int A, int B) {
  __shared__ unsigned hist[256], suff[256];
  __shared__ unsigned sSel; __shared__ int sKr;
  __shared__ float sred[256]; __shared__ unsigned sredc[256];
  int b = blockIdx.x, tid = threadIdx.x;
  int np = (int)cntPos[b], nn = (int)cntNeg[b];
  int ratio = (np>0) ? min(3, A/np) : 0;
  int k = min(ratio*np, nn);
  float negSum = 0.f;
  if (k > 0) {
    int m = min((int)bucketCnt[b], CAP);
    int kr = (int)kremG[b];
    unsigned prefix = 0;
    const unsigned* buf = bucketBuf + b*CAP;
    for (int r=0;r<4;++r) {
      int shift = 24-8*r;
      unsigned maskHi = (r==0) ? 0u : (0xFFFFFFFFu << (32-8*r));
      hist[tid] = 0; __syncthreads();
      for (int i=tid;i<m;i+=256) {
        unsigned v = buf[i];
        if ((v & maskHi) == prefix) atomicAdd(&hist[(v>>shift)&0xFFu], 1u);
      }
      __syncthreads();
      suff[tid] = hist[tid]; __syncthreads();
      for (int off=1;off<256;off<<=1) {
        unsigned v = (tid+off<256) ? suff[tid+off] : 0u;
        __syncthreads(); suff[tid] += v; __syncthreads();
      }
      unsigned incl = suff[tid];
      unsigned above = (tid==255) ? 0u : suff[tid+1];
      if (incl >= (unsigned)kr && above < (unsigned)kr) { sSel=(unsigned)tid; sKr = kr-(int)above; }
      __syncthreads();
      prefix |= (sSel << shift); kr = sKr;
      __syncthreads();
    }
    unsigned theta = prefix;
    float ls=0.f; unsigned lc=0;
    for (int i=tid;i<m;i+=256) {
      unsigned v = buf[i];
      if (v > theta) { ls += focal_neg(__uint_as_float(v)); lc++; }
    }
    sred[tid]=ls; sredc[tid]=lc; __syncthreads();
    for (int s=128;s>0;s>>=1){
      if (tid<s){ sred[tid]+=sred[tid+s]; sredc[tid]+=sredc[tid+s]; }
      __syncthreads();
    }
    int krem = (int)kremG[b];
    negSum = sumHi[b] + sred[0] + (float)(krem-(int)sredc[0]) * focal_neg(__uint_as_float(theta));
  }
  if (tid==0) {
    float confL = (accPos[b] + negSum) / (float)max(np + k, 1);
    float bboxL = accBbox[b] / (float)(np > 0 ? np : 1);
    atomicAdd(out, (confL + bboxL) / (float)B);
  }
}

extern "C" void kernel_launch(void* const* d_in, const int* in_sizes, int n_in,
                              void* d_out, int out_size, void* d_ws, size_t ws_size,
                              hipStream_t stream) {
  const float4* bbox_pred = (const float4*)d_in[0];
  const float*  conf_pred = (const float*)d_in[1];
  const float4* anchors   = (const float4*)d_in[2];
  const float4* tboxes    = (const float4*)d_in[3];
  float* out = (float*)d_out;

  int A = in_sizes[2] / 4;          // 65536
  int B = in_sizes[1] / A;          // 16
  int T = in_sizes[3] / (4 * B);    // 32
  int nch = A / ACH;                // 128
  size_t BA = (size_t)B * A;

  // ws: negConf f32[BA] | maxIou f32[BA] | forced u8[BA] | bestT u8[BA] |
  //     parts[B*T*nch] | gh u32[B*NBIN] | bucketBuf u32[B*CAP] | small accs
  float* negConf = (float*)d_ws;
  float* maxIou  = negConf + BA;
  unsigned char* forced = (unsigned char*)(maxIou + BA);
  unsigned char* bestT  = forced + BA;
  Part* parts = (Part*)(bestT + BA);
  unsigned* gh = (unsigned*)(parts + (size_t)B*T*nch);
  unsigned* bucketBuf = gh + (size_t)B*NBIN;
  float* accPos  = (float*)(bucketBuf + (size_t)B*CAP);
  float* accBbox = accPos + B;
  unsigned* cntPos = (unsigned*)(accBbox + B);
  unsigned* cntNeg = cntPos + B;
  float* sumHi = (float*)(cntNeg + B);
  unsigned* bucketCnt = (unsigned*)(sumHi + B);
  unsigned* kremG = bucketCnt + B;

  int naccW = 7 * B;   // accPos..kremG contiguous words

  dim3 gf((unsigned)nch, (unsigned)B);
  k_fpart<<<gf, 256, 0, stream>>>(anchors, tboxes, parts, maxIou, bestT,
                                  forced, gh, (unsigned*)accPos, naccW, out, A, T, nch);
  k_fmerge<<<B*T, 64, 0, stream>>>(parts, anchors, tboxes, forced, A, T, nch);

  dim3 g2((unsigned)(A/4096), (unsigned)B);
  k_anchor2<<<g2, 256, 0, stream>>>(bbox_pred, conf_pred, tboxes, forced, maxIou, bestT,
                                    negConf, gh, accPos, accBbox, cntPos, cntNeg, A, T);

  dim3 gc(16, (unsigned)B);
  k_collect<<<gc, 256, 0, stream>>>(negConf, gh, cntPos, cntNeg,
                                    sumHi, bucketCnt, bucketBuf, kremG, A, B);
  k_resolve<<<B, 256, 0, stream>>>(bucketBuf, bucketCnt, kremG, sumHi,
                                   accPos, accBbox, cntPos, cntNeg, out, A, B);
}

// Round 11
// 83.293 us; speedup vs baseline: 1.0125x; 1.0125x over previous
//
#include <hip/hip_runtime.h>
#include <math.h>

#define EPSF 1e-6f
#define ACH 1024     // anchors per k_fpart block (4/thread)
#define NBIN 1024    // conf histogram bins
#define CAP 8192     // cutoff-bucket capacity (expected ~64 for uniform conf)
#define CAPB 64      // per-target per-block candidate buffer
#define BIASU 0x4000000000000000ull

struct Part { unsigned long long q0, q1, q2, cand; };

__device__ __forceinline__ double u2d(unsigned long long x){return __longlong_as_double((long long)x);}
__device__ __forceinline__ unsigned long long d2u(double x){return (unsigned long long)__double_as_longlong(x);}

// branchless sorted-insert into descending triple; keys are positive doubles
// (bit62 bias, f32-iou bits occupy bits 32..61) so f64 order == u64 order.
__device__ __forceinline__ void ins3d(double p, double &q0, double &q1, double &q2) {
  double n0 = fmax(q0,p), x = fmin(q0,p);
  double n1 = fmax(q1,x), y = fmin(q1,x);
  double n2 = fmax(q2,y);
  q0=n0; q1=n1; q2=n2;
}

__device__ __forceinline__ float focal_neg(float c) {
  float pt = 1.f - c;
  float ptc = fminf(fmaxf(pt, EPSF), 1.f - EPSF);
  float om = 1.f - pt;
  return -0.75f * om * om * logf(ptc);
}

// Fused per-(1024-anchor-chunk, image) kernel. 4 anchors/thread in registers
// (4 independent argmax chains); targets are block-uniform loads. Per pair:
// IoU core -> argmax (cross-mult compare; precise div at end, np-bitwise) and
// branchless candidate test inter > 0.3*d (== iou>0.3 up to 1ulp boundary).
// Candidates (~2% of pairs) push rcp-ordered keys to per-target LDS buffers;
// 32-thread merge folds to top-3. Exact counts; exact fallback rescans
// overflowed targets (~never). Absorbs k_zero.
__global__ __launch_bounds__(256, 4) void k_fpart(
    const float4* __restrict__ anchors, const float4* __restrict__ tboxes,
    Part* __restrict__ parts, float* __restrict__ maxIou, unsigned char* __restrict__ bestT,
    unsigned char* __restrict__ forced, unsigned* __restrict__ gh,
    unsigned* __restrict__ accW, int naccW, float* __restrict__ out,
    int A, int T, int nch) {
  __shared__ unsigned long long buf[32][CAPB+1];
  __shared__ unsigned cnt[32];
  int chunk = blockIdx.x, b = blockIdx.y;
  int tid = threadIdx.x;
  int base = chunk * ACH;
  // ---- absorbed zero duties ----
  if (tid < 32) cnt[tid] = 0;
  ((unsigned*)(forced + (size_t)b*A + base))[tid] = 0u;   // 256 words = 1024 B
  if (chunk < 4) gh[b*NBIN + chunk*256 + tid] = 0u;
  if (chunk == 4 && b == 0) {
    if (tid < naccW) accW[tid] = 0u;
    if (tid == 0) out[0] = 0.f;
  }
  // ---- 4 anchors to registers (coalesced) ----
  int i0 = base + tid;
  float4 a0 = anchors[i0], a1 = anchors[i0+256], a2 = anchors[i0+512], a3 = anchors[i0+768];
  float ar0=(a0.z-a0.x)*(a0.w-a0.y), ar1=(a1.z-a1.x)*(a1.w-a1.y);
  float ar2=(a2.z-a2.x)*(a2.w-a2.y), ar3=(a3.z-a3.x)*(a3.w-a3.y);
  __syncthreads();           // cnt ready before pushes
  float bn0=-1.f,bd0=1.f, bn1=-1.f,bd1=1.f, bn2=-1.f,bd2=1.f, bn3=-1.f,bd3=1.f;
  int bt0=0, bt1=0, bt2=0, bt3=0;

#define PROC(av, arv, bnv, bdv, btv, idxv) { \
    float ix1=fmaxf(av.x,tv.x), iy1=fmaxf(av.y,tv.y); \
    float ix2=fminf(av.z,tv.z), iy2=fminf(av.w,tv.w); \
    float inter=fmaxf(ix2-ix1,0.f)*fmaxf(iy2-iy1,0.f); \
    float sa = arv + ta; \
    float u = sa - inter, d = u + EPSF;           /* np op order */ \
    bool gt = inter*bdv > bnv*d;                  /* first-occurrence argmax */ \
    bnv=gt?inter:bnv; bdv=gt?d:bdv; btv=gt?tt:btv; \
    if (__builtin_expect(inter > 0.3f*d, 0)) {    /* == iou>0.3 up to 1ulp */ \
      float iou = inter * __builtin_amdgcn_rcpf(d); \
      unsigned slot = atomicAdd(&cnt[tt], 1u); \
      if (slot < CAPB) \
        buf[tt][slot] = ((unsigned long long)__float_as_uint(iou)<<32) \
                      | (unsigned long long)(0xFFFFFFFFu-(unsigned)(idxv)) | BIASU; \
    } \
  }

  #pragma unroll 4
  for (int tt = 0; tt < T; ++tt) {
    float4 tv = tboxes[b*T + tt];          // uniform -> scalar load
    float ta = (tv.z-tv.x)*(tv.w-tv.y);
    PROC(a0, ar0, bn0, bd0, bt0, i0)
    PROC(a1, ar1, bn1, bd1, bt1, i0+256)
    PROC(a2, ar2, bn2, bd2, bt2, i0+512)
    PROC(a3, ar3, bn3, bd3, bt3, i0+768)
  }
#undef PROC
  size_t gb = (size_t)b * A;
  maxIou[gb+i0    ] = bn0/bd0; bestT[gb+i0    ] = (unsigned char)bt0;  // precise, np-bitwise
  maxIou[gb+i0+256] = bn1/bd1; bestT[gb+i0+256] = (unsigned char)bt1;
  maxIou[gb+i0+512] = bn2/bd2; bestT[gb+i0+512] = (unsigned char)bt2;
  maxIou[gb+i0+768] = bn3/bd3; bestT[gb+i0+768] = (unsigned char)bt3;
  __syncthreads();
  const double BIASD = u2d(BIASU);
  if (tid < 32 && tid < T) {               // per-target merge (entries ~20)
    unsigned n = cnt[tid];
    if (n <= CAPB) {
      double q0=BIASD, q1=BIASD, q2=BIASD;
      for (unsigned j = 0; j < n; ++j) ins3d(u2d(buf[tid][j]), q0,q1,q2);
      Part p; p.q0=d2u(q0); p.q1=d2u(q1); p.q2=d2u(q2); p.cand=n;
      parts[(b*T+tid)*nch+chunk] = p;
    }
  }
  if (tid < 64) {                          // exact overflow fallback (~never)
    unsigned long long ovf = __ballot(tid < T && cnt[tid] > CAPB);
    while (ovf) {
      int t = __ffsll(ovf) - 1;
      ovf &= ovf - 1;
      float4 tv = tboxes[b*T + t];
      float ta = (tv.z-tv.x)*(tv.w-tv.y);
      double q0=BIASD, q1=BIASD, q2=BIASD;
      for (int j = 0; j < ACH; j += 64) {
        int idx = base + j + tid;
        float4 an = anchors[idx];
        float aa = (an.z-an.x)*(an.w-an.y);
        float ix1=fmaxf(an.x,tv.x), iy1=fmaxf(an.y,tv.y);
        float ix2=fminf(an.z,tv.z), iy2=fminf(an.w,tv.w);
        float inter=fmaxf(ix2-ix1,0.f)*fmaxf(iy2-iy1,0.f);
        float d = (aa+ta)-inter + EPSF;
        if (inter > 0.3f*d) {
          float iou = inter / d;
          unsigned long long pk = ((unsigned long long)__float_as_uint(iou)<<32)
                                | (unsigned long long)(0xFFFFFFFFu-(unsigned)idx) | BIASU;
          ins3d(u2d(pk), q0,q1,q2);
        }
      }
      for (int s=1;s<64;s<<=1) {
        double r0=__shfl_xor(q0,s,64), r1=__shfl_xor(q1,s,64), r2=__shfl_xor(q2,s,64);
        ins3d(r0,q0,q1,q2); ins3d(r1,q0,q1,q2); ins3d(r2,q0,q1,q2);
      }
      if (tid == 0) {
        Part p; p.q0=d2u(q0); p.q1=d2u(q1); p.q2=d2u(q2); p.cand=cnt[t];
        parts[(b*T+t)*nch+chunk] = p;
      }
    }
  }
}

// one wave per (b,t): merge nch chunk-partials. cand>=1: forced = top-min(3,cand)
// (== reference, since forced set is within candidates). cand==0: exact argmax.
__global__ __launch_bounds__(64) void k_fmerge(
    const Part* __restrict__ parts, const float4* __restrict__ anchors,
    const float4* __restrict__ tboxes, unsigned char* __restrict__ forced,
    int A, int T, int nch) {
  int p = blockIdx.x;            // b*T + t
  int b = p / T, t = p - b*T;
  int lane = threadIdx.x;
  const double BIASD = u2d(BIASU);
  double q0=BIASD, q1=BIASD, q2=BIASD;
  unsigned long long cand = 0;
  for (int c = lane; c < nch; c += 64) {
    Part pp = parts[p*nch + c];
    ins3d(u2d(pp.q0),q0,q1,q2); ins3d(u2d(pp.q1),q0,q1,q2); ins3d(u2d(pp.q2),q0,q1,q2);
    cand += pp.cand;
  }
  for (int s = 1; s < 64; s <<= 1) {
    double r0=__shfl_xor(q0,s,64), r1=__shfl_xor(q1,s,64), r2=__shfl_xor(q2,s,64);
    unsigned long long rc=__shfl_xor(cand,s,64);
    ins3d(r0,q0,q1,q2); ins3d(r1,q0,q1,q2); ins3d(r2,q0,q1,q2);
    cand += rc;
  }
  if (cand == 0) {               // wave-uniform, ~never taken
    float4 tv = tboxes[b*T + t];
    float ta = (tv.z-tv.x)*(tv.w-tv.y);
    double m = BIASD;
    for (int a = lane; a < A; a += 64) {
      float4 an = anchors[a];
      float a1 = (an.z-an.x)*(an.w-an.y);
      float ix1=fmaxf(an.x,tv.x), iy1=fmaxf(an.y,tv.y);
      float ix2=fminf(an.z,tv.z), iy2=fminf(an.w,tv.w);
      float inter=fmaxf(ix2-ix1,0.f)*fmaxf(iy2-iy1,0.f);
      float u = (a1 + ta) - inter;
      float iou = inter / (u + EPSF);
      unsigned long long pk = ((unsigned long long)__float_as_uint(iou)<<32)
                            | (unsigned long long)(0xFFFFFFFFu-(unsigned)a) | BIASU;
      m = fmax(m, u2d(pk));
    }
    for (int s = 1; s < 64; s <<= 1) m = fmax(m, __shfl_xor(m, s, 64));
    if (lane == 0) {
      unsigned idx = 0xFFFFFFFFu - (unsigned)(d2u(m) & 0xFFFFFFFFull);
      forced[(size_t)b*A + idx] = 1;
    }
  } else if (lane == 0) {
    int kt = cand > 3 ? 3 : (int)cand;
    unsigned long long tp[3] = {d2u(q0), d2u(q1), d2u(q2)};
    for (int j = 0; j < kt; ++j) {
      unsigned idx = 0xFFFFFFFFu - (unsigned)(tp[j] & 0xFFFFFFFFull);
      forced[(size_t)b*A + idx] = 1;
    }
  }
}

// streaming: 16 anchors/thread. Reads maxIou/bestT/forced/conf (+bbox for positives),
// writes negConf, builds per-image conf histogram (LDS->global), accumulates
// focal/bbox sums + counts.
__global__ __launch_bounds__(256) void k_anchor2(
    const float4* __restrict__ bbox_pred, const float* __restrict__ conf_pred,
    const float4* __restrict__ tboxes,
    const unsigned char* __restrict__ forced, const float* __restrict__ maxIou,
    const unsigned char* __restrict__ bestT,
    float* __restrict__ negConf, unsigned* __restrict__ gh,
    float* __restrict__ accPos, float* __restrict__ accBbox,
    unsigned* __restrict__ cntPos, unsigned* __restrict__ cntNeg,
    int A, int T) {
  __shared__ float4 st[32];
  __shared__ unsigned h[NBIN];
  __shared__ float sP[256], sB[256];
  __shared__ int cP[256], cN[256];
  int b = blockIdx.y, tid = threadIdx.x;
  if (tid < T) st[tid] = tboxes[b*T+tid];
  for (int i = tid; i < NBIN; i += 256) h[i] = 0;
  __syncthreads();
  size_t ibase = (size_t)b*A + (size_t)blockIdx.x*4096;
  float fsum=0.f, bsum=0.f; int cpos=0, cneg=0;
  for (int it = 0; it < 4; ++it) {
    int off = it*1024 + tid*4;
    float4 mi4 = *(const float4*)(maxIou + ibase + off);
    float4 cf4 = *(const float4*)(conf_pred + ibase + off);
    uchar4 fc4 = *(const uchar4*)(forced + ibase + off);
    uchar4 bt4 = *(const uchar4*)(bestT + ibase + off);
    float mis[4]={mi4.x,mi4.y,mi4.z,mi4.w};
    float cfs[4]={cf4.x,cf4.y,cf4.z,cf4.w};
    unsigned char fcs[4]={fc4.x,fc4.y,fc4.z,fc4.w};
    unsigned char bts[4]={bt4.x,bt4.y,bt4.z,bt4.w};
    float nc[4];
    #pragma unroll
    for (int j=0;j<4;++j) {
      float maxI = mis[j], conf = cfs[j];
      bool isPos = (maxI >= 0.5f) || (fcs[j] != 0);
      bool isNeg = (maxI < 0.4f) && !isPos;
      nc[j] = isNeg ? conf : -1.f;
      if (isNeg) {
        int bin = min(NBIN-1, (int)(conf*1024.f));
        atomicAdd(&h[bin], 1u);
        cneg++;
      }
      if (isPos) {
        cpos++;
        float ptc = fminf(fmaxf(conf, EPSF), 1.f-EPSF);
        float om = 1.f - conf;
        fsum += -0.25f * om * om * logf(ptc);
        float4 pb = bbox_pred[ibase + off + j];
        float4 m = st[bts[j]];
        float ix1=fmaxf(pb.x,m.x), iy1=fmaxf(pb.y,m.y);
        float ix2=fminf(pb.z,m.z), iy2=fminf(pb.w,m.w);
        float inter=fmaxf(ix2-ix1,0.f)*fmaxf(iy2-iy1,0.f);
        float a1=(pb.z-pb.x)*(pb.w-pb.y);
        float a2=(m.z-m.x)*(m.w-m.y);
        float uni = a1 + a2 - inter;
        float iou = inter/(uni+EPSF);
        float ex1=fminf(pb.x,m.x), ey1=fminf(pb.y,m.y);
        float ex2=fmaxf(pb.z,m.z), ey2=fmaxf(pb.w,m.w);
        float enc=(ex2-ex1)*(ey2-ey1);
        float giou = iou - (enc-uni)/(enc+EPSF);
        float l1 = fabsf(pb.x-m.x)+fabsf(pb.y-m.y)+fabsf(pb.z-m.z)+fabsf(pb.w-m.w);
        bsum += (1.f - giou) + 0.125f*l1;
      }
    }
    *(float4*)(negConf + ibase + off) = make_float4(nc[0],nc[1],nc[2],nc[3]);
  }
  sP[tid]=fsum; sB[tid]=bsum; cP[tid]=cpos; cN[tid]=cneg;
  __syncthreads();
  for (int s=128;s>0;s>>=1) {
    if (tid<s){ sP[tid]+=sP[tid+s]; sB[tid]+=sB[tid+s]; cP[tid]+=cP[tid+s]; cN[tid]+=cN[tid+s]; }
    __syncthreads();
  }
  if (tid==0) {
    atomicAdd(&accPos[b], sP[0]);
    atomicAdd(&accBbox[b], sB[0]);
    atomicAdd(&cntPos[b], (unsigned)cP[0]);
    atomicAdd(&cntNeg[b], (unsigned)cN[0]);
  }
  for (int i = tid; i < NBIN; i += 256)
    if (h[i]) atomicAdd(&gh[b*NBIN + i], h[i]);
}

// 16 blocks/image: redundant parallel hist-scan -> selB/krem, then stream slice:
// focal-sum for bins > selB, collect cutoff-bucket members to global.
__global__ __launch_bounds__(256) void k_collect(
    const float* __restrict__ negConf, const unsigned* __restrict__ gh,
    const unsigned* __restrict__ cntPos, const unsigned* __restrict__ cntNeg,
    float* __restrict__ sumHi, unsigned* __restrict__ bucketCnt,
    unsigned* __restrict__ bucketBuf, unsigned* __restrict__ kremG,
    int A, int B) {
  __shared__ unsigned hh[NBIN];
  __shared__ unsigned partial[256];
  __shared__ int sSelB, sKrem;
  __shared__ float sred[256];
  int b = blockIdx.y, tid = threadIdx.x;
  int np = (int)cntPos[b], nn = (int)cntNeg[b];
  int ratio = (np>0) ? min(3, A/np) : 0;
  int k = min(ratio*np, nn);
  if (k <= 0) return;
  for (int i = tid; i < NBIN; i += 256) hh[i] = gh[b*NBIN+i];
  __syncthreads();
  unsigned own = hh[4*tid] + hh[4*tid+1] + hh[4*tid+2] + hh[4*tid+3];
  partial[tid] = own;
  __syncthreads();
  for (int off=1; off<256; off<<=1) {       // inclusive suffix scan (parallel)
    unsigned v = (tid+off<256) ? partial[tid+off] : 0u;
    __syncthreads();
    partial[tid] += v;
    __syncthreads();
  }
  {
    unsigned running = partial[tid] - own;  // sum of bins >= 4(tid+1)
    #pragma unroll
    for (int j=3;j>=0;--j) {
      unsigned incl = running + hh[4*tid+j];
      if (incl >= (unsigned)k && running < (unsigned)k) { sSelB = 4*tid+j; sKrem = k-(int)running; }
      running = incl;
    }
  }
  __syncthreads();
  int selB = sSelB, krem = sKrem;
  if (blockIdx.x==0 && tid==0) kremG[b] = (unsigned)krem;
  const float4* nc4 = (const float4*)(negConf + (size_t)b*A);
  int per4 = (A/4) / gridDim.x;
  int i0 = blockIdx.x * per4;
  float ls = 0.f;
  for (int i = tid; i < per4; i += 256) {
    float4 c4 = nc4[i0+i];
    float cs[4]={c4.x,c4.y,c4.z,c4.w};
    #pragma unroll
    for (int j=0;j<4;++j) {
      float c = cs[j];
      if (c >= 0.f) {
        int bin = min(NBIN-1, (int)(c*1024.f));
        if (bin > selB) ls += focal_neg(c);
        else if (bin == selB) {
          unsigned idx = atomicAdd(&bucketCnt[b], 1u);
          if (idx < CAP) bucketBuf[b*CAP+idx] = __float_as_uint(c);
        }
      }
    }
  }
  sred[tid]=ls; __syncthreads();
  for (int s=128;s>0;s>>=1){ if(tid<s) sred[tid]+=sred[tid+s]; __syncthreads(); }
  if (tid==0) atomicAdd(&sumHi[b], sred[0]);
}

// one block/image: fully parallel radix-select over the small bucket -> exact
// theta; finalize scalar.
__global__ __launch_bounds__(256) void k_resolve(
    const unsigned* __restrict__ bucketBuf, const unsigned* __restrict__ bucketCnt,
    const unsigned* __restrict__ kremG, const float* __restrict__ sumHi,
    const float* __restrict__ accPos, const float* __restrict__ accBbox,
    const unsigned* __restrict__ cntPos, const unsigned* __restrict__ cntNeg,
    float* __restrict__ out, int A, int B) {
  __shared__ unsigned hist[256], suff[256];
  __shared__ unsigned sSel; __shared__ int sKr;
  __shared__ float sred[256]; __shared__ unsigned sredc[256];
  int b = blockIdx.x, tid = threadIdx.x;
  int np = (int)cntPos[b], nn = (int)cntNeg[b];
  int ratio = (np>0) ? min(3, A/np) : 0;
  int k = min(ratio*np, nn);
  float negSum = 0.f;
  if (k > 0) {
    int m = min((int)bucketCnt[b], CAP);
    int kr = (int)kremG[b];
    unsigned prefix = 0;
    const unsigned* buf = bucketBuf + b*CAP;
    for (int r=0;r<4;++r) {
      int shift = 24-8*r;
      unsigned maskHi = (r==0) ? 0u : (0xFFFFFFFFu << (32-8*r));
      hist[tid] = 0; __syncthreads();
      for (int i=tid;i<m;i+=256) {
        unsigned v = buf[i];
        if ((v & maskHi) == prefix) atomicAdd(&hist[(v>>shift)&0xFFu], 1u);
      }
      __syncthreads();
      suff[tid] = hist[tid]; __syncthreads();
      for (int off=1;off<256;off<<=1) {
        unsigned v = (tid+off<256) ? suff[tid+off] : 0u;
        __syncthreads(); suff[tid] += v; __syncthreads();
      }
      unsigned incl = suff[tid];
      unsigned above = (tid==255) ? 0u : suff[tid+1];
      if (incl >= (unsigned)kr && above < (unsigned)kr) { sSel=(unsigned)tid; sKr = kr-(int)above; }
      __syncthreads();
      prefix |= (sSel << shift); kr = sKr;
      __syncthreads();
    }
    unsigned theta = prefix;
    float ls=0.f; unsigned lc=0;
    for (int i=tid;i<m;i+=256) {
      unsigned v = buf[i];
      if (v > theta) { ls += focal_neg(__uint_as_float(v)); lc++; }
    }
    sred[tid]=ls; sredc[tid]=lc; __syncthreads();
    for (int s=128;s>0;s>>=1){
      if (tid<s){ sred[tid]+=sred[tid+s]; sredc[tid]+=sredc[tid+s]; }
      __syncthreads();
    }
    int krem = (int)kremG[b];
    negSum = sumHi[b] + sred[0] + (float)(krem-(int)sredc[0]) * focal_neg(__uint_as_float(theta));
  }
  if (tid==0) {
    float confL = (accPos[b] + negSum) / (float)max(np + k, 1);
    float bboxL = accBbox[b] / (float)(np > 0 ? np : 1);
    atomicAdd(out, (confL + bboxL) / (float)B);
  }
}

extern "C" void kernel_launch(void* const* d_in, const int* in_sizes, int n_in,
                              void* d_out, int out_size, void* d_ws, size_t ws_size,
                              hipStream_t stream) {
  const float4* bbox_pred = (const float4*)d_in[0];
  const float*  conf_pred = (const float*)d_in[1];
  const float4* anchors   = (const float4*)d_in[2];
  const float4* tboxes    = (const float4*)d_in[3];
  float* out = (float*)d_out;

  int A = in_sizes[2] / 4;          // 65536
  int B = in_sizes[1] / A;          // 16
  int T = in_sizes[3] / (4 * B);    // 32
  int nch = A / ACH;                // 64
  size_t BA = (size_t)B * A;

  // ws: negConf f32[BA] | maxIou f32[BA] | forced u8[BA] | bestT u8[BA] |
  //     parts[B*T*nch] | gh u32[B*NBIN] | bucketBuf u32[B*CAP] | small accs
  float* negConf = (float*)d_ws;
  float* maxIou  = negConf + BA;
  unsigned char* forced = (unsigned char*)(maxIou + BA);
  unsigned char* bestT  = forced + BA;
  Part* parts = (Part*)(bestT + BA);
  unsigned* gh = (unsigned*)(parts + (size_t)B*T*nch);
  unsigned* bucketBuf = gh + (size_t)B*NBIN;
  float* accPos  = (float*)(bucketBuf + (size_t)B*CAP);
  float* accBbox = accPos + B;
  unsigned* cntPos = (unsigned*)(accBbox + B);
  unsigned* cntNeg = cntPos + B;
  float* sumHi = (float*)(cntNeg + B);
  unsigned* bucketCnt = (unsigned*)(sumHi + B);
  unsigned* kremG = bucketCnt + B;

  int naccW = 7 * B;   // accPos..kremG contiguous words

  dim3 gf((unsigned)nch, (unsigned)B);
  k_fpart<<<gf, 256, 0, stream>>>(anchors, tboxes, parts, maxIou, bestT,
                                  forced, gh, (unsigned*)accPos, naccW, out, A, T, nch);
  k_fmerge<<<B*T, 64, 0, stream>>>(parts, anchors, tboxes, forced, A, T, nch);

  dim3 g2((unsigned)(A/4096), (unsigned)B);
  k_anchor2<<<g2, 256, 0, stream>>>(bbox_pred, conf_pred, tboxes, forced, maxIou, bestT,
                                    negConf, gh, accPos, accBbox, cntPos, cntNeg, A, T);

  dim3 gc(16, (unsigned)B);
  k_collect<<<gc, 256, 0, stream>>>(negConf, gh, cntPos, cntNeg,
                                    sumHi, bucketCnt, bucketBuf, kremG, A, B);
  k_resolve<<<B, 256, 0, stream>>>(bucketBuf, bucketCnt, kremG, sumHi,
                                   accPos, accBbox, cntPos, cntNeg, out, A, B);
}